// Round 1
// baseline (469.676 us; speedup 1.0000x reference)
//
#include <hip/hip_runtime.h>

// Fused 16-expert, 2-layer Linear+ReLU stack.
//   x  [524288, 128] fp32   -> 16 slices of 32768 tokens
//   W  [16, 2, 128, 128] fp32 (torch [out,in] layout)
//   b  [16, 2, 128] fp32
//   out[n,g] = relu( relu(x W0^T + b0) W1^T + b1 )   per expert slice
//
// Strategy: bf16 MFMA (16x16x32), both layers fused in one kernel so the
// intermediate never touches HBM. Block = 256 thr (4 waves) x 64 tokens of
// one expert. W staged per layer into LDS as bf16; x loaded directly from
// global into A fragments; layer-1 output round-trips through LDS to convert
// C/D layout -> A layout.

#define NF   128
#define NM   16
#define NTOK 524288
#define TPM  (NTOK / NM)     // 32768 tokens per model
#define BM   64              // tokens per block
#define WPAD 136             // row pitch (bf16 elems): 272 B = 16-B aligned rows

typedef __attribute__((ext_vector_type(8))) short bf16x8;
typedef __attribute__((ext_vector_type(4))) float f32x4;

__device__ __forceinline__ unsigned short f2bf(float f) {
    union { float f; unsigned u; } v; v.f = f;
    unsigned r = v.u + 0x7FFFu + ((v.u >> 16) & 1u);   // RNE
    return (unsigned short)(r >> 16);
}

__global__ __launch_bounds__(256, 2) void mlp16_kernel(
        const float* __restrict__ x, const float* __restrict__ W,
        const float* __restrict__ b, float* __restrict__ out) {
    __shared__ alignas(16) unsigned short sW[NF * WPAD];   // 34816 B, one layer at a time
    __shared__ alignas(16) unsigned short sY[BM * WPAD];   // 17408 B, layer-1 activations
    __shared__ float sB[2 * NF];                           // both biases

    const int t    = threadIdx.x;
    const int wave = t >> 6;
    const int lane = t & 63;
    const int ln   = lane & 15;   // A row / B col / D col within 16-tile
    const int q    = lane >> 4;   // k-quad

    const int m    = blockIdx.x >> 9;      // 512 blocks per model
    const int tile = blockIdx.x & 511;
    const int row0 = m * TPM + tile * BM;

    sB[t] = b[m * 2 * NF + t];  // 256 floats = b[m,0,:] ++ b[m,1,:]

    // ---- stage W0 -> LDS (fp32 -> bf16) ----
    const float4* W0 = (const float4*)(W + (size_t)m * 2 * NF * NF);
    #pragma unroll
    for (int i = 0; i < 16; ++i) {
        int c = t + i * 256;                       // 4096 float4 chunks
        float4 w = W0[c];
        unsigned short* d = &sW[(c >> 5) * WPAD + (c & 31) * 4];
        d[0] = f2bf(w.x); d[1] = f2bf(w.y); d[2] = f2bf(w.z); d[3] = f2bf(w.w);
    }
    __syncthreads();

    // ---- layer 1: A straight from global x, B from sW ----
    f32x4 acc[8];
    #pragma unroll
    for (int gt = 0; gt < 8; ++gt) acc[gt] = (f32x4){0.f, 0.f, 0.f, 0.f};

    const float* xrow = x + (size_t)(row0 + wave * 16 + ln) * NF;
    #pragma unroll
    for (int kt = 0; kt < 4; ++kt) {
        const int f0 = kt * 32 + q * 8;
        float4 a0 = *(const float4*)(xrow + f0);
        float4 a1 = *(const float4*)(xrow + f0 + 4);
        bf16x8 af;
        af[0] = (short)f2bf(a0.x); af[1] = (short)f2bf(a0.y);
        af[2] = (short)f2bf(a0.z); af[3] = (short)f2bf(a0.w);
        af[4] = (short)f2bf(a1.x); af[5] = (short)f2bf(a1.y);
        af[6] = (short)f2bf(a1.z); af[7] = (short)f2bf(a1.w);
        #pragma unroll
        for (int gt = 0; gt < 8; ++gt) {
            bf16x8 bfr = *(const bf16x8*)&sW[(gt * 16 + ln) * WPAD + f0];
            acc[gt] = __builtin_amdgcn_mfma_f32_16x16x32_bf16(af, bfr, acc[gt], 0, 0, 0);
        }
    }

    // bias + relu -> sY (bf16), C/D layout: row = q*4+r, col = ln
    #pragma unroll
    for (int gt = 0; gt < 8; ++gt) {
        const float bias = sB[gt * 16 + ln];
        #pragma unroll
        for (int r = 0; r < 4; ++r) {
            float v = acc[gt][r] + bias;
            v = v > 0.f ? v : 0.f;
            sY[(wave * 16 + q * 4 + r) * WPAD + gt * 16 + ln] = f2bf(v);
        }
    }
    __syncthreads();

    // ---- stage W1 over W0 ----
    const float4* W1 = W0 + (NF * NF / 4);
    #pragma unroll
    for (int i = 0; i < 16; ++i) {
        int c = t + i * 256;
        float4 w = W1[c];
        unsigned short* d = &sW[(c >> 5) * WPAD + (c & 31) * 4];
        d[0] = f2bf(w.x); d[1] = f2bf(w.y); d[2] = f2bf(w.z); d[3] = f2bf(w.w);
    }
    __syncthreads();

    // ---- layer 2: A from sY, B from sW ----
    f32x4 acc2[8];
    #pragma unroll
    for (int gt = 0; gt < 8; ++gt) acc2[gt] = (f32x4){0.f, 0.f, 0.f, 0.f};

    const unsigned short* yrow = &sY[(wave * 16 + ln) * WPAD];
    #pragma unroll
    for (int kt = 0; kt < 4; ++kt) {
        const int f0 = kt * 32 + q * 8;
        bf16x8 af = *(const bf16x8*)(yrow + f0);
        #pragma unroll
        for (int gt = 0; gt < 8; ++gt) {
            bf16x8 bfr = *(const bf16x8*)&sW[(gt * 16 + ln) * WPAD + f0];
            acc2[gt] = __builtin_amdgcn_mfma_f32_16x16x32_bf16(af, bfr, acc2[gt], 0, 0, 0);
        }
    }

    // bias + relu -> global out (fp32)
    #pragma unroll
    for (int gt = 0; gt < 8; ++gt) {
        const float bias = sB[NF + gt * 16 + ln];
        #pragma unroll
        for (int r = 0; r < 4; ++r) {
            float v = acc2[gt][r] + bias;
            v = v > 0.f ? v : 0.f;
            out[(size_t)(row0 + wave * 16 + q * 4 + r) * NF + gt * 16 + ln] = v;
        }
    }
}

extern "C" void kernel_launch(void* const* d_in, const int* in_sizes, int n_in,
                              void* d_out, int out_size, void* d_ws, size_t ws_size,
                              hipStream_t stream) {
    const float* x = (const float*)d_in[0];
    const float* W = (const float*)d_in[1];
    const float* b = (const float*)d_in[2];
    float* out = (float*)d_out;
    mlp16_kernel<<<dim3(NTOK / BM), dim3(256), 0, stream>>>(x, W, b, out);
}